// Round 10
// baseline (1039.717 us; speedup 1.0000x reference)
//
#include <hip/hip_runtime.h>

#define B_ 2
#define S_ 2048
#define E_ 4096
#define NH 32
#define NKV 8
#define DH 128

typedef __attribute__((ext_vector_type(8))) short short8;   // 8 x bf16 (4 VGPRs)
typedef __attribute__((ext_vector_type(4))) float f32x4;    // MFMA 16x16 accumulator

__device__ __forceinline__ unsigned short f2bf(float f) {
  unsigned int u = __float_as_uint(f);
  u += 0x7fffu + ((u >> 16) & 1u);   // RNE
  return (unsigned short)(u >> 16);
}
__device__ __forceinline__ float bf2f(unsigned short u) {
  return __uint_as_float(((unsigned int)u) << 16);
}

// async global->LDS, 16B per lane. LDS dest = wave-uniform base + lane*16.
__device__ __forceinline__ void async16(const void* g, void* l) {
  __builtin_amdgcn_global_load_lds(
      (__attribute__((address_space(1))) void*)const_cast<void*>(g),
      (__attribute__((address_space(3))) void*)l, 16, 0, 0);
}

// ---------------- fp32 -> bf16 elementwise ----------------
__global__ void k_cvt(const float4* __restrict__ in, ushort4* __restrict__ out, int n4) {
  int i = blockIdx.x * blockDim.x + threadIdx.x;
  if (i >= n4) return;
  float4 v = in[i];
  ushort4 o;
  o.x = f2bf(v.x); o.y = f2bf(v.y); o.z = f2bf(v.z); o.w = f2bf(v.w);
  out[i] = o;
}

// ---------------- W (KxN fp32, row-major) -> out (NxK bf16) ----------------
__global__ void k_transpose(const float* __restrict__ in, unsigned short* __restrict__ out,
                            int K, int N) {
  __shared__ float tile[32][33];
  int n0 = blockIdx.x * 32, k0 = blockIdx.y * 32;
  int tx = threadIdx.x, ty = threadIdx.y;  // 32 x 8
#pragma unroll
  for (int j = 0; j < 32; j += 8)
    tile[ty + j][tx] = in[(size_t)(k0 + ty + j) * N + n0 + tx];
  __syncthreads();
#pragma unroll
  for (int j = 0; j < 32; j += 8)
    out[(size_t)(n0 + ty + j) * K + k0 + tx] = f2bf(tile[tx][ty + j]);
}

// ---------------- RoPE in-place on (B, heads, S, D) bf16 ----------------
__global__ void k_rope(unsigned short* buf, int heads, const int* __restrict__ pos) {
  int i = blockIdx.x * blockDim.x + threadIdx.x;
  int d = i & 63;
  int s = (i >> 6) & (S_ - 1);
  int bh = i >> 17;                 // S_*64 = 2^17 per (b,head)
  int b = bh / heads;
  float p = (float)pos[b * S_ + s];
  // inv_freq = 10000^(-d/64);  ln(10000)/64 = 0.14391156831212787
  float fr = p * expf(-0.14391156831212787f * (float)d);
  float c, sn;
  sincosf(fr, &sn, &c);
  size_t base = ((size_t)bh * S_ + s) * DH;
  float x1 = bf2f(buf[base + d]);
  float x2 = bf2f(buf[base + d + 64]);
  buf[base + d]      = f2bf(x1 * c - x2 * sn);
  buf[base + d + 64] = f2bf(x2 * c + x1 * sn);
}

// ---------------- GEMM: A(MxK bf16 row-major) x Bt(NxK bf16) ----------------
// r1-proven schedule (128x128 tile, 4 waves, ONE __syncthreads per iter,
// stage->other-buffer WAR ledger) with BK=64 (r4-verified, 917 us total).
template <int MODE>
__global__ __launch_bounds__(256) void k_gemm(
    const unsigned short* __restrict__ A, const unsigned short* __restrict__ Bt, int K,
    const float* __restrict__ bq, const float* __restrict__ bk, const float* __restrict__ bv,
    unsigned short* __restrict__ Qo, unsigned short* __restrict__ Ko,
    unsigned short* __restrict__ Vo, float* __restrict__ Co) {
  __shared__ __align__(16) unsigned short As[2][128 * 64];   // 2 x 16 KB
  __shared__ __align__(16) unsigned short Bs[2][128 * 64];   // 2 x 16 KB
  const int tid = threadIdx.x;
  const int wave = tid >> 6, lane = tid & 63;
  const int l15 = lane & 15, quad = lane >> 4;
  const int bid = blockIdx.x;
  const int m0 = (bid & 31) * 128, n0 = (bid >> 5) * 128;
  const int wm = (wave & 1) * 64, wn = (wave >> 1) * 64;

  f32x4 acc[4][4] = {};

  // staging: 16B-slot index e = j*256+tid over the 128x64 tile (8 slots/row)
  auto stage = [&](int p, int k0) {
#pragma unroll
    for (int j = 0; j < 4; ++j) {
      const int e = j * 256 + tid;
      const int row = e >> 3, sl = e & 7;
      const int gseg = sl ^ (row & 7);
      async16(A + (size_t)(m0 + row) * K + k0 + gseg * 8,
              &As[p][(size_t)(j * 256 + wave * 64) * 8]);
      async16(Bt + (size_t)(n0 + row) * K + k0 + gseg * 8,
              &Bs[p][(size_t)(j * 256 + wave * 64) * 8]);
    }
  };

  stage(0, 0);
  int p = 0;
  for (int k0 = 0; k0 < K; k0 += 64) {
    __syncthreads();                 // drains vmcnt -> buf p certified
    if (k0 + 64 < K) stage(p ^ 1, k0 + 64);   // prefetch next tile (other buf)
#pragma unroll
    for (int kk = 0; kk < 2; ++kk) {
      short8 af[4], bfr[4];
#pragma unroll
      for (int i = 0; i < 4; ++i)
        af[i] = *(const short8*)&As[p][(wm + i * 16 + l15) * 64 +
                                       (((kk << 2) + quad) ^ (l15 & 7)) * 8];
#pragma unroll
      for (int i = 0; i < 4; ++i)
        bfr[i] = *(const short8*)&Bs[p][(wn + i * 16 + l15) * 64 +
                                        (((kk << 2) + quad) ^ (l15 & 7)) * 8];
#pragma unroll
      for (int mi = 0; mi < 4; ++mi)
#pragma unroll
        for (int ni = 0; ni < 4; ++ni)
          acc[mi][ni] = __builtin_amdgcn_mfma_f32_16x16x32_bf16(af[mi], bfr[ni], acc[mi][ni], 0, 0, 0);
    }
    p ^= 1;
  }

#pragma unroll
  for (int mi = 0; mi < 4; ++mi) {
#pragma unroll
    for (int ni = 0; ni < 4; ++ni) {
      const int col = n0 + wn + ni * 16 + l15;
      const int rowb = m0 + wm + mi * 16 + quad * 4;
      if constexpr (MODE == 1) {
#pragma unroll
        for (int r = 0; r < 4; ++r)
          Co[(size_t)(rowb + r) * E_ + col] = acc[mi][ni][r];
      } else {
#pragma unroll
        for (int r = 0; r < 4; ++r) {
          const int row = rowb + r;
          const int b = row >> 11, s = row & (S_ - 1);
          float v = acc[mi][ni][r];
          if (col < 4096) {           // Q: (B,NH,S,D)
            v += bq[col];
            const int h = col >> 7, d = col & 127;
            Qo[(((size_t)b * NH + h) * S_ + s) * DH + d] = f2bf(v);
          } else if (col < 5120) {    // K: (B,NKV,S,D)
            const int t = col - 4096;
            v += bk[t];
            const int h = t >> 7, d = t & 127;
            Ko[(((size_t)b * NKV + h) * S_ + s) * DH + d] = f2bf(v);
          } else {                    // V^T: (B,NKV,D,S)
            const int t = col - 5120;
            v += bv[t];
            const int h = t >> 7, d = t & 127;
            Vo[(((size_t)b * NKV + h) * DH + d) * S_ + s] = f2bf(v);
          }
        }
      }
    }
  }
}

// ---------------- flash attention: Br=64, Bc=128, causal ----------------
// Geometry = the best-measured r4/r7 shape (287-290 us): Bc=128 minimizes
// iteration count, which r8/r9 proved is what time scales with (per-iter
// serial VALU chain: softmax reduce + rescale + P roundtrip; staging latency
// already hidden by TLP - r9 double-buffer was null). This round cuts the
// serial chain itself:
//  (1) exp2-domain softmax: scale' = scale*log2(e), exp2f replaces expf
//      (drops the per-exp hidden multiply; identical values).
//  (2) defer-max (T13): skip max-update + alpha + of-rescale when no row max
//      grew by >8 (P bounded by 2^8=256; f32 l/O headroom ample; first tile
//      always takes the heavy path since mrow=-1e30).
// LPT qt remap kept (time-neutral, -18% FETCH).
// Q (B,NH,S,D), K (B,NKV,S,D), Vt (B,NKV,D,S) -> O (B,S,NH,D)   all bf16
__global__ __launch_bounds__(256) void k_attn(
    const unsigned short* __restrict__ Q, const unsigned short* __restrict__ Kb,
    const unsigned short* __restrict__ Vt, unsigned short* __restrict__ O) {
  __shared__ unsigned short Ks[128 * 128];  // 32KB, xor-swizzled 16B slots
  __shared__ unsigned short Vs[128 * 128];  // 32KB
  __shared__ unsigned short Ps[64 * 128];   // 16KB, per-wave 16 rows
  const int tid = threadIdx.x;
  const int wave = tid >> 6, lane = tid & 63;
  const int l15 = lane & 15, quad = lane >> 4;
  const int bid = blockIdx.x;
  const int t5 = bid & 31;          // S/64 slots
  const int qt = (t5 & 1) ? (t5 >> 1) : 31 - (t5 >> 1);  // LPT pairing
  const int h = (bid >> 5) & 31;
  const int b = bid >> 10;
  const int kvh = h >> 2;           // H/KVH = 4
  const int q0 = qt * 64;

  const unsigned short* Qp = Q + ((size_t)b * NH + h) * S_ * DH;
  const unsigned short* Kp = Kb + ((size_t)b * NKV + kvh) * S_ * DH;
  const unsigned short* Vp = Vt + ((size_t)b * NKV + kvh) * DH * (size_t)S_;

  // Q fragments in registers: wave's 16 q-rows, A-layout [m=l15][k=quad*8+j]
  short8 qf[4];
  {
    const unsigned short* qp = Qp + (size_t)(q0 + wave * 16 + l15) * DH + quad * 8;
#pragma unroll
    for (int kk = 0; kk < 4; ++kk) qf[kk] = *(const short8*)(qp + kk * 32);
  }

  f32x4 of[8] = {};
  float mrow[4], lrow[4];
#pragma unroll
  for (int r = 0; r < 4; ++r) { mrow[r] = -1e30f; lrow[r] = 0.f; }

  const int jmax = q0 >> 7;
  // 1/sqrt(128) * log2(e): softmax computed in exp2 domain
  const float scale = 0.1275174335f;
  unsigned short* Pw = &Ps[wave * 16 * 128];

  for (int j = 0; j <= jmax; ++j) {
    const int kv0 = j * 128;
    // stage K tile [kv][d] and V^T tile [d][kv]; slot = seg ^ (row&15)
#pragma unroll
    for (int r = 0; r < 8; ++r) {
      const int e = r * 256 + wave * 64 + lane;
      const int row = e >> 4, slot = e & 15;
      const int gseg = slot ^ (row & 15);
      async16(Kp + (size_t)(kv0 + row) * DH + gseg * 8, &Ks[(size_t)(r * 256 + wave * 64) * 8]);
    }
#pragma unroll
    for (int r = 0; r < 8; ++r) {
      const int e = r * 256 + wave * 64 + lane;
      const int row = e >> 4, slot = e & 15;
      const int gseg = slot ^ (row & 15);
      async16(Vp + (size_t)row * S_ + kv0 + gseg * 8, &Vs[(size_t)(r * 256 + wave * 64) * 8]);
    }
    __syncthreads();

    // S = Q K^T  (rows = wave's 16 q, cols = 128 kv)
    f32x4 sf[8];
#pragma unroll
    for (int ni = 0; ni < 8; ++ni) {
      f32x4 a = {};
#pragma unroll
      for (int kk = 0; kk < 4; ++kk) {
        const int rowi = ni * 16 + l15;
        short8 kf = *(const short8*)&Ks[rowi * 128 + ((kk * 4 + quad) ^ l15) * 8];
        a = __builtin_amdgcn_mfma_f32_16x16x32_bf16(qf[kk], kf, a, 0, 0, 0);
      }
      sf[ni] = a * scale;
    }

    if (j == jmax) {  // causal boundary tile
#pragma unroll
      for (int ni = 0; ni < 8; ++ni) {
        const int col = kv0 + ni * 16 + l15;
#pragma unroll
        for (int r = 0; r < 4; ++r) {
          const int row = q0 + wave * 16 + quad * 4 + r;
          if (col > row) sf[ni][r] = -1e30f;
        }
      }
    }

    // online softmax (exp2 domain); row m = quad*4 + r, 16 lanes share a row
    float cm[4];
    bool need = false;
#pragma unroll
    for (int r = 0; r < 4; ++r) {
      float c0 = sf[0][r];
#pragma unroll
      for (int ni = 1; ni < 8; ++ni) c0 = fmaxf(c0, sf[ni][r]);
      c0 = fmaxf(c0, __shfl_xor(c0, 1));
      c0 = fmaxf(c0, __shfl_xor(c0, 2));
      c0 = fmaxf(c0, __shfl_xor(c0, 4));
      c0 = fmaxf(c0, __shfl_xor(c0, 8));
      cm[r] = c0;
      need = need || (c0 > mrow[r] + 8.0f);
    }
    if (__any(need)) {   // heavy path: rescale to the new max
#pragma unroll
      for (int r = 0; r < 4; ++r) {
        const float nm = fmaxf(mrow[r], cm[r]);
        const float alpha = __builtin_amdgcn_exp2f(mrow[r] - nm);
        mrow[r] = nm;
        float rs = 0.f;
#pragma unroll
        for (int ni = 0; ni < 8; ++ni) {
          const float pv = __builtin_amdgcn_exp2f(sf[ni][r] - nm);
          sf[ni][r] = pv;
          rs += pv;
        }
        rs += __shfl_xor(rs, 1);
        rs += __shfl_xor(rs, 2);
        rs += __shfl_xor(rs, 4);
        rs += __shfl_xor(rs, 8);
        lrow[r] = lrow[r] * alpha + rs;
#pragma unroll
        for (int ni = 0; ni < 8; ++ni) of[ni][r] *= alpha;
      }
    } else {             // light path: keep old max (P <= 2^8), no rescale
#pragma unroll
      for (int r = 0; r < 4; ++r) {
        float rs = 0.f;
#pragma unroll
        for (int ni = 0; ni < 8; ++ni) {
          const float pv = __builtin_amdgcn_exp2f(sf[ni][r] - mrow[r]);
          sf[ni][r] = pv;
          rs += pv;
        }
        rs += __shfl_xor(rs, 1);
        rs += __shfl_xor(rs, 2);
        rs += __shfl_xor(rs, 4);
        rs += __shfl_xor(rs, 8);
        lrow[r] += rs;
      }
    }

    // P (C-layout) -> LDS bf16 (swizzled), then read back as A-layout.
    // Truncating bf16 convert: relative error ~2^-8, fine for P (<= 256).
#pragma unroll
    for (int ni = 0; ni < 8; ++ni) {
#pragma unroll
      for (int r = 0; r < 4; ++r) {
        const int pr = quad * 4 + r;
        const int c = ni * 16 + l15;
        const int slot = (c >> 3) ^ pr;
        Pw[pr * 128 + slot * 8 + (c & 7)] =
            (unsigned short)(__float_as_uint(sf[ni][r]) >> 16);
      }
    }
    short8 pf[4];
#pragma unroll
    for (int kk = 0; kk < 4; ++kk)
      pf[kk] = *(const short8*)&Pw[l15 * 128 + ((kk * 4 + quad) ^ l15) * 8];

    // O += P V   (B operand = V^T rows: [n=d][k=kv])
#pragma unroll
    for (int ni = 0; ni < 8; ++ni) {
#pragma unroll
      for (int kk = 0; kk < 4; ++kk) {
        const int rowi = ni * 16 + l15;
        short8 vf = *(const short8*)&Vs[rowi * 128 + ((kk * 4 + quad) ^ l15) * 8];
        of[ni] = __builtin_amdgcn_mfma_f32_16x16x32_bf16(pf[kk], vf, of[ni], 0, 0, 0);
      }
    }
    __syncthreads();  // before next tile overwrites Ks/Vs
  }

  float il[4];
#pragma unroll
  for (int r = 0; r < 4; ++r) il[r] = 1.0f / lrow[r];
#pragma unroll
  for (int ni = 0; ni < 8; ++ni) {
#pragma unroll
    for (int r = 0; r < 4; ++r) {
      const int row = q0 + wave * 16 + quad * 4 + r;
      const int d = ni * 16 + l15;
      O[(((size_t)b * S_ + row) * NH + h) * DH + d] = f2bf(of[ni][r] * il[r]);
    }
  }
}

extern "C" void kernel_launch(void* const* d_in, const int* in_sizes, int n_in,
                              void* d_out, int out_size, void* d_ws, size_t ws_size,
                              hipStream_t stream) {
  const float* hs = (const float*)d_in[0];
  // d_in[1] attention_mask: causal, applied analytically in k_attn
  const int* pos = (const int*)d_in[2];
  const float* Wq = (const float*)d_in[3];
  const float* bq = (const float*)d_in[4];
  const float* Wk = (const float*)d_in[5];
  const float* bk = (const float*)d_in[6];
  const float* Wv = (const float*)d_in[7];
  const float* bv = (const float*)d_in[8];
  const float* Wo = (const float*)d_in[9];
  float* out = (float*)d_out;

  // ws layout (128 MB):
  //   [0,32M):    X bf16 (4096x4096), reused as O (B,S,NH,D) after QKV GEMM
  //   [32M,80M):  WT bf16 (6144x4096) = [Wq^T;Wk^T;Wv^T], reused as Wo^T later
  //   [80M,112M): Q (B,NH,S,D)
  //   [112M,120M):K (B,NKV,S,D)
  //   [120M,128M):V^T (B,NKV,D,S)
  unsigned char* ws = (unsigned char*)d_ws;
  unsigned short* X   = (unsigned short*)(ws);
  unsigned short* WT  = (unsigned short*)(ws + 33554432ull);
  unsigned short* Qb  = (unsigned short*)(ws + 83886080ull);
  unsigned short* Kb  = (unsigned short*)(ws + 117440512ull);
  unsigned short* Vtb = (unsigned short*)(ws + 125829120ull);
  unsigned short* Ob  = X;    // reuse after QKV GEMM done reading X
  unsigned short* WoT = WT;   // reuse after QKV GEMM done reading WT

  dim3 tb(32, 8);
  k_cvt<<<16384, 256, 0, stream>>>((const float4*)hs, (ushort4*)X, 4194304);
  k_transpose<<<dim3(128, 128), tb, 0, stream>>>(Wq, WT, 4096, 4096);
  k_transpose<<<dim3(32, 128), tb, 0, stream>>>(Wk, WT + 4096ull * 4096ull, 4096, 1024);
  k_transpose<<<dim3(32, 128), tb, 0, stream>>>(Wv, WT + 5120ull * 4096ull, 4096, 1024);
  k_gemm<0><<<32 * 48, 256, 0, stream>>>(X, WT, 4096, bq, bk, bv, Qb, Kb, Vtb, nullptr);
  k_transpose<<<dim3(128, 128), tb, 0, stream>>>(Wo, WoT, 4096, 4096);  // after QKV GEMM (region reuse)
  k_rope<<<32768, 256, 0, stream>>>(Qb, NH, pos);
  k_rope<<<8192, 256, 0, stream>>>(Kb, NKV, pos);
  k_attn<<<2048, 256, 0, stream>>>(Qb, Kb, Vtb, Ob);
  k_gemm<1><<<32 * 32, 256, 0, stream>>>(Ob, WoT, 4096,
                                         nullptr, nullptr, nullptr,
                                         nullptr, nullptr, nullptr, out);
}

// Round 11
// 895.601 us; speedup vs baseline: 1.1609x; 1.1609x over previous
//
#include <hip/hip_runtime.h>

#define B_ 2
#define S_ 2048
#define E_ 4096
#define NH 32
#define NKV 8
#define DH 128

typedef __attribute__((ext_vector_type(8))) short short8;   // 8 x bf16 (4 VGPRs)
typedef __attribute__((ext_vector_type(4))) float f32x4;    // MFMA 16x16 accumulator

__device__ __forceinline__ unsigned short f2bf(float f) {
  unsigned int u = __float_as_uint(f);
  u += 0x7fffu + ((u >> 16) & 1u);   // RNE
  return (unsigned short)(u >> 16);
}
__device__ __forceinline__ float bf2f(unsigned short u) {
  return __uint_as_float(((unsigned int)u) << 16);
}

// async global->LDS, 16B per lane. LDS dest = wave-uniform base + lane*16.
__device__ __forceinline__ void async16(const void* g, void* l) {
  __builtin_amdgcn_global_load_lds(
      (__attribute__((address_space(1))) void*)const_cast<void*>(g),
      (__attribute__((address_space(3))) void*)l, 16, 0, 0);
}

// ---------------- fp32 -> bf16 elementwise ----------------
__global__ void k_cvt(const float4* __restrict__ in, ushort4* __restrict__ out, int n4) {
  int i = blockIdx.x * blockDim.x + threadIdx.x;
  if (i >= n4) return;
  float4 v = in[i];
  ushort4 o;
  o.x = f2bf(v.x); o.y = f2bf(v.y); o.z = f2bf(v.z); o.w = f2bf(v.w);
  out[i] = o;
}

// ---------------- W (KxN fp32, row-major) -> out (NxK bf16) ----------------
__global__ void k_transpose(const float* __restrict__ in, unsigned short* __restrict__ out,
                            int K, int N) {
  __shared__ float tile[32][33];
  int n0 = blockIdx.x * 32, k0 = blockIdx.y * 32;
  int tx = threadIdx.x, ty = threadIdx.y;  // 32 x 8
#pragma unroll
  for (int j = 0; j < 32; j += 8)
    tile[ty + j][tx] = in[(size_t)(k0 + ty + j) * N + n0 + tx];
  __syncthreads();
#pragma unroll
  for (int j = 0; j < 32; j += 8)
    out[(size_t)(n0 + ty + j) * K + k0 + tx] = f2bf(tile[tx][ty + j]);
}

// ---------------- RoPE in-place on (B, heads, S, D) bf16 ----------------
__global__ void k_rope(unsigned short* buf, int heads, const int* __restrict__ pos) {
  int i = blockIdx.x * blockDim.x + threadIdx.x;
  int d = i & 63;
  int s = (i >> 6) & (S_ - 1);
  int bh = i >> 17;                 // S_*64 = 2^17 per (b,head)
  int b = bh / heads;
  float p = (float)pos[b * S_ + s];
  // inv_freq = 10000^(-d/64);  ln(10000)/64 = 0.14391156831212787
  float fr = p * expf(-0.14391156831212787f * (float)d);
  float c, sn;
  sincosf(fr, &sn, &c);
  size_t base = ((size_t)bh * S_ + s) * DH;
  float x1 = bf2f(buf[base + d]);
  float x2 = bf2f(buf[base + d + 64]);
  buf[base + d]      = f2bf(x1 * c - x2 * sn);
  buf[base + d + 64] = f2bf(x2 * c + x1 * sn);
}

// ---------------- GEMM: A(MxK bf16 row-major) x Bt(NxK bf16) ----------------
// r1-proven schedule (128x128 tile, 4 waves, ONE __syncthreads per iter,
// stage->other-buffer WAR ledger) with BK=64 (r4-verified, 917 us total).
template <int MODE>
__global__ __launch_bounds__(256) void k_gemm(
    const unsigned short* __restrict__ A, const unsigned short* __restrict__ Bt, int K,
    const float* __restrict__ bq, const float* __restrict__ bk, const float* __restrict__ bv,
    unsigned short* __restrict__ Qo, unsigned short* __restrict__ Ko,
    unsigned short* __restrict__ Vo, float* __restrict__ Co) {
  __shared__ __align__(16) unsigned short As[2][128 * 64];   // 2 x 16 KB
  __shared__ __align__(16) unsigned short Bs[2][128 * 64];   // 2 x 16 KB
  const int tid = threadIdx.x;
  const int wave = tid >> 6, lane = tid & 63;
  const int l15 = lane & 15, quad = lane >> 4;
  const int bid = blockIdx.x;
  const int m0 = (bid & 31) * 128, n0 = (bid >> 5) * 128;
  const int wm = (wave & 1) * 64, wn = (wave >> 1) * 64;

  f32x4 acc[4][4] = {};

  // staging: 16B-slot index e = j*256+tid over the 128x64 tile (8 slots/row)
  auto stage = [&](int p, int k0) {
#pragma unroll
    for (int j = 0; j < 4; ++j) {
      const int e = j * 256 + tid;
      const int row = e >> 3, sl = e & 7;
      const int gseg = sl ^ (row & 7);
      async16(A + (size_t)(m0 + row) * K + k0 + gseg * 8,
              &As[p][(size_t)(j * 256 + wave * 64) * 8]);
      async16(Bt + (size_t)(n0 + row) * K + k0 + gseg * 8,
              &Bs[p][(size_t)(j * 256 + wave * 64) * 8]);
    }
  };

  stage(0, 0);
  int p = 0;
  for (int k0 = 0; k0 < K; k0 += 64) {
    __syncthreads();                 // drains vmcnt -> buf p certified
    if (k0 + 64 < K) stage(p ^ 1, k0 + 64);   // prefetch next tile (other buf)
#pragma unroll
    for (int kk = 0; kk < 2; ++kk) {
      short8 af[4], bfr[4];
#pragma unroll
      for (int i = 0; i < 4; ++i)
        af[i] = *(const short8*)&As[p][(wm + i * 16 + l15) * 64 +
                                       (((kk << 2) + quad) ^ (l15 & 7)) * 8];
#pragma unroll
      for (int i = 0; i < 4; ++i)
        bfr[i] = *(const short8*)&Bs[p][(wn + i * 16 + l15) * 64 +
                                        (((kk << 2) + quad) ^ (l15 & 7)) * 8];
#pragma unroll
      for (int mi = 0; mi < 4; ++mi)
#pragma unroll
        for (int ni = 0; ni < 4; ++ni)
          acc[mi][ni] = __builtin_amdgcn_mfma_f32_16x16x32_bf16(af[mi], bfr[ni], acc[mi][ni], 0, 0, 0);
    }
    p ^= 1;
  }

#pragma unroll
  for (int mi = 0; mi < 4; ++mi) {
#pragma unroll
    for (int ni = 0; ni < 4; ++ni) {
      const int col = n0 + wn + ni * 16 + l15;
      const int rowb = m0 + wm + mi * 16 + quad * 4;
      if constexpr (MODE == 1) {
#pragma unroll
        for (int r = 0; r < 4; ++r)
          Co[(size_t)(rowb + r) * E_ + col] = acc[mi][ni][r];
      } else {
#pragma unroll
        for (int r = 0; r < 4; ++r) {
          const int row = rowb + r;
          const int b = row >> 11, s = row & (S_ - 1);
          float v = acc[mi][ni][r];
          if (col < 4096) {           // Q: (B,NH,S,D)
            v += bq[col];
            const int h = col >> 7, d = col & 127;
            Qo[(((size_t)b * NH + h) * S_ + s) * DH + d] = f2bf(v);
          } else if (col < 5120) {    // K: (B,NKV,S,D)
            const int t = col - 4096;
            v += bk[t];
            const int h = t >> 7, d = t & 127;
            Ko[(((size_t)b * NKV + h) * S_ + s) * DH + d] = f2bf(v);
          } else {                    // V^T: (B,NKV,D,S)
            const int t = col - 5120;
            v += bv[t];
            const int h = t >> 7, d = t & 127;
            Vo[(((size_t)b * NKV + h) * DH + d) * S_ + s] = f2bf(v);
          }
        }
      }
    }
  }
}

// ---------------- flash attention: Br=64, Bc=128, causal ----------------
// EXACT r7 structure (290 us, VGPR 124 -> 2 blocks/CU). r10 taught the law:
// VGPR>128 halves occupancy (11.8->6.3%) and costs +120us — so this round's
// changes are strictly register-neutral:
//  (1) exp2-domain softmax: scale' = scale*log2(e); exp2f replaces expf
//      (removes the per-exp hidden v_mul; single path, no new live values).
//  (2) T5 s_setprio(1) around the MFMA clusters: 2 independent blocks/CU at
//      different phases = the m191 regime where setprio paid (not m190's
//      lockstep null).
// LPT qt remap kept (time-neutral, -18% FETCH).
// Q (B,NH,S,D), K (B,NKV,S,D), Vt (B,NKV,D,S) -> O (B,S,NH,D)   all bf16
__global__ __launch_bounds__(256) void k_attn(
    const unsigned short* __restrict__ Q, const unsigned short* __restrict__ Kb,
    const unsigned short* __restrict__ Vt, unsigned short* __restrict__ O) {
  __shared__ unsigned short Ks[128 * 128];  // 32KB, xor-swizzled 16B slots
  __shared__ unsigned short Vs[128 * 128];  // 32KB
  __shared__ unsigned short Ps[64 * 128];   // 16KB, per-wave 16 rows
  const int tid = threadIdx.x;
  const int wave = tid >> 6, lane = tid & 63;
  const int l15 = lane & 15, quad = lane >> 4;
  const int bid = blockIdx.x;
  const int t5 = bid & 31;          // S/64 slots
  const int qt = (t5 & 1) ? (t5 >> 1) : 31 - (t5 >> 1);  // LPT pairing
  const int h = (bid >> 5) & 31;
  const int b = bid >> 10;
  const int kvh = h >> 2;           // H/KVH = 4
  const int q0 = qt * 64;

  const unsigned short* Qp = Q + ((size_t)b * NH + h) * S_ * DH;
  const unsigned short* Kp = Kb + ((size_t)b * NKV + kvh) * S_ * DH;
  const unsigned short* Vp = Vt + ((size_t)b * NKV + kvh) * DH * (size_t)S_;

  // Q fragments in registers: wave's 16 q-rows, A-layout [m=l15][k=quad*8+j]
  short8 qf[4];
  {
    const unsigned short* qp = Qp + (size_t)(q0 + wave * 16 + l15) * DH + quad * 8;
#pragma unroll
    for (int kk = 0; kk < 4; ++kk) qf[kk] = *(const short8*)(qp + kk * 32);
  }

  f32x4 of[8] = {};
  float mrow[4], lrow[4];
#pragma unroll
  for (int r = 0; r < 4; ++r) { mrow[r] = -1e30f; lrow[r] = 0.f; }

  const int jmax = q0 >> 7;
  // 1/sqrt(128) * log2(e): softmax computed in exp2 domain
  const float scale = 0.1275174335f;
  unsigned short* Pw = &Ps[wave * 16 * 128];

  for (int j = 0; j <= jmax; ++j) {
    const int kv0 = j * 128;
    // stage K tile [kv][d] and V^T tile [d][kv]; slot = seg ^ (row&15)
#pragma unroll
    for (int r = 0; r < 8; ++r) {
      const int e = r * 256 + wave * 64 + lane;
      const int row = e >> 4, slot = e & 15;
      const int gseg = slot ^ (row & 15);
      async16(Kp + (size_t)(kv0 + row) * DH + gseg * 8, &Ks[(size_t)(r * 256 + wave * 64) * 8]);
    }
#pragma unroll
    for (int r = 0; r < 8; ++r) {
      const int e = r * 256 + wave * 64 + lane;
      const int row = e >> 4, slot = e & 15;
      const int gseg = slot ^ (row & 15);
      async16(Vp + (size_t)row * S_ + kv0 + gseg * 8, &Vs[(size_t)(r * 256 + wave * 64) * 8]);
    }
    __syncthreads();

    // S = Q K^T  (rows = wave's 16 q, cols = 128 kv)
    f32x4 sf[8];
    __builtin_amdgcn_s_setprio(1);
#pragma unroll
    for (int ni = 0; ni < 8; ++ni) {
      f32x4 a = {};
#pragma unroll
      for (int kk = 0; kk < 4; ++kk) {
        const int rowi = ni * 16 + l15;
        short8 kf = *(const short8*)&Ks[rowi * 128 + ((kk * 4 + quad) ^ l15) * 8];
        a = __builtin_amdgcn_mfma_f32_16x16x32_bf16(qf[kk], kf, a, 0, 0, 0);
      }
      sf[ni] = a * scale;
    }
    __builtin_amdgcn_s_setprio(0);

    if (j == jmax) {  // causal boundary tile
#pragma unroll
      for (int ni = 0; ni < 8; ++ni) {
        const int col = kv0 + ni * 16 + l15;
#pragma unroll
        for (int r = 0; r < 4; ++r) {
          const int row = q0 + wave * 16 + quad * 4 + r;
          if (col > row) sf[ni][r] = -1e30f;
        }
      }
    }

    // online softmax (exp2 domain); row m = quad*4 + r, 16 lanes share a row
#pragma unroll
    for (int r = 0; r < 4; ++r) {
      float cm = sf[0][r];
#pragma unroll
      for (int ni = 1; ni < 8; ++ni) cm = fmaxf(cm, sf[ni][r]);
      cm = fmaxf(cm, __shfl_xor(cm, 1));
      cm = fmaxf(cm, __shfl_xor(cm, 2));
      cm = fmaxf(cm, __shfl_xor(cm, 4));
      cm = fmaxf(cm, __shfl_xor(cm, 8));
      const float nm = fmaxf(mrow[r], cm);
      const float alpha = __builtin_amdgcn_exp2f(mrow[r] - nm);
      mrow[r] = nm;
      float rs = 0.f;
#pragma unroll
      for (int ni = 0; ni < 8; ++ni) {
        const float pv = __builtin_amdgcn_exp2f(sf[ni][r] - nm);
        sf[ni][r] = pv;
        rs += pv;
      }
      rs += __shfl_xor(rs, 1);
      rs += __shfl_xor(rs, 2);
      rs += __shfl_xor(rs, 4);
      rs += __shfl_xor(rs, 8);
      lrow[r] = lrow[r] * alpha + rs;
#pragma unroll
      for (int ni = 0; ni < 8; ++ni) of[ni][r] *= alpha;
    }

    // P (C-layout) -> LDS bf16 (swizzled), then read back as A-layout.
    // P in [0,1]: truncating bf16 convert (1 VALU) is fine accuracy-wise.
#pragma unroll
    for (int ni = 0; ni < 8; ++ni) {
#pragma unroll
      for (int r = 0; r < 4; ++r) {
        const int pr = quad * 4 + r;
        const int c = ni * 16 + l15;
        const int slot = (c >> 3) ^ pr;
        Pw[pr * 128 + slot * 8 + (c & 7)] =
            (unsigned short)(__float_as_uint(sf[ni][r]) >> 16);
      }
    }
    short8 pf[4];
#pragma unroll
    for (int kk = 0; kk < 4; ++kk)
      pf[kk] = *(const short8*)&Pw[l15 * 128 + ((kk * 4 + quad) ^ l15) * 8];

    // O += P V   (B operand = V^T rows: [n=d][k=kv])
    __builtin_amdgcn_s_setprio(1);
#pragma unroll
    for (int ni = 0; ni < 8; ++ni) {
#pragma unroll
      for (int kk = 0; kk < 4; ++kk) {
        const int rowi = ni * 16 + l15;
        short8 vf = *(const short8*)&Vs[rowi * 128 + ((kk * 4 + quad) ^ l15) * 8];
        of[ni] = __builtin_amdgcn_mfma_f32_16x16x32_bf16(pf[kk], vf, of[ni], 0, 0, 0);
      }
    }
    __builtin_amdgcn_s_setprio(0);
    __syncthreads();  // before next tile overwrites Ks/Vs
  }

  float il[4];
#pragma unroll
  for (int r = 0; r < 4; ++r) il[r] = 1.0f / lrow[r];
#pragma unroll
  for (int ni = 0; ni < 8; ++ni) {
#pragma unroll
    for (int r = 0; r < 4; ++r) {
      const int row = q0 + wave * 16 + quad * 4 + r;
      const int d = ni * 16 + l15;
      O[(((size_t)b * S_ + row) * NH + h) * DH + d] = f2bf(of[ni][r] * il[r]);
    }
  }
}

extern "C" void kernel_launch(void* const* d_in, const int* in_sizes, int n_in,
                              void* d_out, int out_size, void* d_ws, size_t ws_size,
                              hipStream_t stream) {
  const float* hs = (const float*)d_in[0];
  // d_in[1] attention_mask: causal, applied analytically in k_attn
  const int* pos = (const int*)d_in[2];
  const float* Wq = (const float*)d_in[3];
  const float* bq = (const float*)d_in[4];
  const float* Wk = (const float*)d_in[5];
  const float* bk = (const float*)d_in[6];
  const float* Wv = (const float*)d_in[7];
  const float* bv = (const float*)d_in[8];
  const float* Wo = (const float*)d_in[9];
  float* out = (float*)d_out;

  // ws layout (128 MB):
  //   [0,32M):    X bf16 (4096x4096), reused as O (B,S,NH,D) after QKV GEMM
  //   [32M,80M):  WT bf16 (6144x4096) = [Wq^T;Wk^T;Wv^T], reused as Wo^T later
  //   [80M,112M): Q (B,NH,S,D)
  //   [112M,120M):K (B,NKV,S,D)
  //   [120M,128M):V^T (B,NKV,D,S)
  unsigned char* ws = (unsigned char*)d_ws;
  unsigned short* X   = (unsigned short*)(ws);
  unsigned short* WT  = (unsigned short*)(ws + 33554432ull);
  unsigned short* Qb  = (unsigned short*)(ws + 83886080ull);
  unsigned short* Kb  = (unsigned short*)(ws + 117440512ull);
  unsigned short* Vtb = (unsigned short*)(ws + 125829120ull);
  unsigned short* Ob  = X;    // reuse after QKV GEMM done reading X
  unsigned short* WoT = WT;   // reuse after QKV GEMM done reading WT

  dim3 tb(32, 8);
  k_cvt<<<16384, 256, 0, stream>>>((const float4*)hs, (ushort4*)X, 4194304);
  k_transpose<<<dim3(128, 128), tb, 0, stream>>>(Wq, WT, 4096, 4096);
  k_transpose<<<dim3(32, 128), tb, 0, stream>>>(Wk, WT + 4096ull * 4096ull, 4096, 1024);
  k_transpose<<<dim3(32, 128), tb, 0, stream>>>(Wv, WT + 5120ull * 4096ull, 4096, 1024);
  k_gemm<0><<<32 * 48, 256, 0, stream>>>(X, WT, 4096, bq, bk, bv, Qb, Kb, Vtb, nullptr);
  k_transpose<<<dim3(128, 128), tb, 0, stream>>>(Wo, WoT, 4096, 4096);  // after QKV GEMM (region reuse)
  k_rope<<<32768, 256, 0, stream>>>(Qb, NH, pos);
  k_rope<<<8192, 256, 0, stream>>>(Kb, NKV, pos);
  k_attn<<<2048, 256, 0, stream>>>(Qb, Kb, Vtb, Ob);
  k_gemm<1><<<32 * 32, 256, 0, stream>>>(Ob, WoT, 4096,
                                         nullptr, nullptr, nullptr,
                                         nullptr, nullptr, nullptr, out);
}